// Round 4
// baseline (817.955 us; speedup 1.0000x reference)
//
#include <hip/hip_runtime.h>

#define BB 2
#define LL 4096
#define DD 128
#define HH 4

typedef unsigned short u16;
typedef unsigned int u32;
typedef __attribute__((ext_vector_type(8))) short short8;   // 8 bf16
typedef __attribute__((ext_vector_type(4))) float floatx4;

__device__ __forceinline__ u16 f2bf(float f) {
    union { float f; u32 u; } v; v.f = f;
    return (u16)((v.u + 0x7fffu + ((v.u >> 16) & 1u)) >> 16);
}

__global__ __launch_bounds__(256) void cvt_all(const float* __restrict__ x,
                                               const float* __restrict__ wq,
                                               const float* __restrict__ wk,
                                               const float* __restrict__ wv,
                                               const float* __restrict__ wo,
                                               u16* xb, u16* wqb, u16* wkb,
                                               u16* wvb, u16* wob) {
    int z = blockIdx.y;
    const float* src; u16* dst; int n;
    if      (z == 0) { src = x;  dst = xb;  n = BB * LL * DD; }
    else if (z == 1) { src = wq; dst = wqb; n = HH * DD * DD; }
    else if (z == 2) { src = wk; dst = wkb; n = HH * DD * DD; }
    else if (z == 3) { src = wv; dst = wvb; n = HH * DD * DD; }
    else             { src = wo; dst = wob; n = DD * HH * DD; }
    int i = (blockIdx.x * 256 + threadIdx.x) * 4;
    if (i >= n) return;
    float4 v = *(const float4*)(src + i);
    ushort4 o;
    o.x = f2bf(v.x); o.y = f2bf(v.y); o.z = f2bf(v.z); o.w = f2bf(v.w);
    *(ushort4*)(dst + i) = o;
}

// Fused QKV projection. z=0: Q row-major [B,H,L,E]; z=1: K row-major;
// z=2: V transposed [B,H,E,L] via MFMA operand swap.
__global__ __launch_bounds__(256) void proj_qkv(const u16* __restrict__ xb,
                                                const u16* __restrict__ wqb,
                                                const u16* __restrict__ wkb,
                                                const u16* __restrict__ wvb,
                                                u16* __restrict__ Qb,
                                                u16* __restrict__ Kb,
                                                u16* __restrict__ Vt) {
    int z = blockIdx.z;
    const u16* w = (z == 0) ? wqb : (z == 1) ? wkb : wvb;
    u16* out     = (z == 0) ? Qb  : (z == 1) ? Kb  : Vt;
    int lane = threadIdx.x & 63;
    int w4   = threadIdx.x >> 6;
    int c = lane & 15, g = lane >> 4;
    int mt = blockIdx.x;
    int nt = blockIdx.y * 4 + w4;

    const u16* xp = xb + (mt * 16 + c) * DD + g * 8;
    const u16* wp = w  + (nt * 16 + c) * DD + g * 8;

    floatx4 acc = {0.f, 0.f, 0.f, 0.f};
    if (z < 2) {
#pragma unroll
        for (int kk = 0; kk < 4; kk++) {
            short8 a = *(const short8*)(xp + kk * 32);
            short8 b = *(const short8*)(wp + kk * 32);
            acc = __builtin_amdgcn_mfma_f32_16x16x32_bf16(a, b, acc, 0, 0, 0);
        }
        int n = nt * 16 + c;
        int h = n >> 7, e = n & 127;
#pragma unroll
        for (int r = 0; r < 4; r++) {
            int m = mt * 16 + g * 4 + r;
            int b_ = m >> 12, l = m & 4095;
            out[((b_ * HH + h) * LL + l) * DD + e] = f2bf(acc[r]);
        }
    } else {
#pragma unroll
        for (int kk = 0; kk < 4; kk++) {
            short8 a = *(const short8*)(wp + kk * 32);
            short8 b = *(const short8*)(xp + kk * 32);
            acc = __builtin_amdgcn_mfma_f32_16x16x32_bf16(a, b, acc, 0, 0, 0);
        }
        int lg = mt * 16 + c;
        int b_ = lg >> 12, l = lg & 4095;
        int n0 = nt * 16;
        int h = n0 >> 7, e0 = n0 & 127;
#pragma unroll
        for (int r = 0; r < 4; r++) {
            out[((b_ * HH + h) * DD + e0 + g * 4 + r) * LL + l] = f2bf(acc[r]);
        }
    }
}

// Flash attention, causal, no-max softmax, additive chunk combine.
// Block = 8 waves = 128 q rows of one head; all waves share the same K/V
// tile each step (identical addresses -> L1 dedup), kept converged by one
// __syncthreads per step. K chunked in 1024-key slabs, longest-first.
__global__ __launch_bounds__(512, 6) void flash_attn(const u16* __restrict__ Q,
                                                     const u16* __restrict__ K,
                                                     const u16* __restrict__ Vt,
                                                     float* __restrict__ ctx_acc,
                                                     float* __restrict__ l_acc) {
    int lane = threadIdx.x & 63;
    int wv   = threadIdx.x >> 6;          // 0..7
    int c = lane & 15, g = lane >> 4;

    int bid  = blockIdx.x;
    int head = bid & 7;                   // b*H + h
    int i    = bid >> 3;                  // 0..79
    int t, ch;
    if      (i < 8)  { t = 8 + i;            ch = 0; }
    else if (i < 24) { t = 16 + ((i-8) >> 1); ch = (i-8) & 1; }
    else if (i < 48) { t = 24 + (i-24) / 3;   ch = (i-24) % 3; }
    else { int d = i - 48; int r = 7 - (d >> 2); t = ((d & 3) << 3) + r; ch = d & 3; }

    int b_ = head >> 2, h = head & 3;
    int kstart = ch << 10;
    int kend   = min(t * 128 + 128, kstart + 1024);
    int nsteps = (kend - kstart + 31) >> 5;        // block-uniform

    int qbase = t * 128 + wv * 16;
    int q_c   = qbase + c;
    // wave's personal active-step count (monotone: active then done)
    int my_steps = 0;
    if (kstart <= qbase + 15)
        my_steps = min(nsteps, ((qbase + 15 - kstart) >> 5) + 1);

    // Q as B-fragment (n = c = q-row, k = g*8..)
    const u16* qp = Q + ((size_t)head * LL + qbase + c) * DD + g * 8;
    short8 bq[4];
#pragma unroll
    for (int kk = 0; kk < 4; kk++) bq[kk] = *(const short8*)(qp + kk * 32);

    const u16* kp  = K  + ((size_t)head * LL + kstart + c) * DD + g * 8;
    const u16* vp0 = Vt + ((size_t)head * DD + c) * LL + kstart + g * 8;

    floatx4 o[8];
#pragma unroll
    for (int tt = 0; tt < 8; tt++) o[tt] = (floatx4){0.f, 0.f, 0.f, 0.f};
    float lsum = 0.f;

    int s0 = c + (((g << 1) & 3) << 4);
    int s1 = c + ((((g << 1) | 1) & 3) << 4);
    bool hi = (g >= 2);

    // preload K for step 0
    short8 ka[8];
    if (my_steps > 0) {
#pragma unroll
        for (int kk = 0; kk < 4; kk++) {
            ka[kk]     = *(const short8*)(kp + kk * 32);
            ka[4 + kk] = *(const short8*)(kp + 16 * DD + kk * 32);
        }
        kp += 32 * DD;
    }

    for (int j = 0; j < nsteps; ++j) {
        __syncthreads();                  // keep 8 waves converged for L1 reuse
        if (j < my_steps) {
            int kb = kstart + (j << 5);
            // V tile for this step (same addrs across all 8 waves)
            short8 vb[8];
#pragma unroll
            for (int tt = 0; tt < 8; tt++)
                vb[tt] = *(const short8*)(vp0 + (size_t)tt * 16 * LL + (j << 5));

            // S^T = K · Q^T
            floatx4 st0 = {0.f,0.f,0.f,0.f}, st1 = {0.f,0.f,0.f,0.f};
#pragma unroll
            for (int kk = 0; kk < 4; kk++) {
                st0 = __builtin_amdgcn_mfma_f32_16x16x32_bf16(ka[kk],     bq[kk], st0, 0, 0, 0);
                st1 = __builtin_amdgcn_mfma_f32_16x16x32_bf16(ka[4 + kk], bq[kk], st1, 0, 0, 0);
            }
            // prefetch next K tile
            if (j + 1 < my_steps) {
#pragma unroll
                for (int kk = 0; kk < 4; kk++) {
                    ka[kk]     = *(const short8*)(kp + kk * 32);
                    ka[4 + kk] = *(const short8*)(kp + 16 * DD + kk * 32);
                }
                kp += 32 * DD;
            }

            // exp (no max subtraction); mask only near the diagonal
            float p[8];
            if (kb + 31 > qbase) {
#pragma unroll
                for (int r = 0; r < 4; r++) {
                    int k0 = kb + g * 4 + r;
                    p[r]     = (k0      <= q_c) ? st0[r] : -INFINITY;
                    p[4 + r] = (k0 + 16 <= q_c) ? st1[r] : -INFINITY;
                }
            } else {
#pragma unroll
                for (int r = 0; r < 4; r++) { p[r] = st0[r]; p[4 + r] = st1[r]; }
            }
#pragma unroll
            for (int i2 = 0; i2 < 8; i2++) { p[i2] = __expf(p[i2]); lsum += p[i2]; }

            // pack P -> bf16 pairs, exchange into PV A-fragment
            u32 pk00 = (u32)f2bf(p[0]) | ((u32)f2bf(p[1]) << 16);
            u32 pk01 = (u32)f2bf(p[2]) | ((u32)f2bf(p[3]) << 16);
            u32 pk10 = (u32)f2bf(p[4]) | ((u32)f2bf(p[5]) << 16);
            u32 pk11 = (u32)f2bf(p[6]) | ((u32)f2bf(p[7]) << 16);
            u32 x00 = (u32)__shfl((int)pk00, s0), x10 = (u32)__shfl((int)pk10, s0);
            u32 x01 = (u32)__shfl((int)pk01, s0), x11 = (u32)__shfl((int)pk11, s0);
            u32 y00 = (u32)__shfl((int)pk00, s1), y10 = (u32)__shfl((int)pk10, s1);
            u32 y01 = (u32)__shfl((int)pk01, s1), y11 = (u32)__shfl((int)pk11, s1);
            union { short8 s; u32 u[4]; } au;
            au.u[0] = hi ? x10 : x00;
            au.u[1] = hi ? x11 : x01;
            au.u[2] = hi ? y10 : y00;
            au.u[3] = hi ? y11 : y01;

#pragma unroll
            for (int tt = 0; tt < 8; tt++)
                o[tt] = __builtin_amdgcn_mfma_f32_16x16x32_bf16(au.s, vb[tt], o[tt], 0, 0, 0);
        }
    }

    if (my_steps > 0) {
        lsum += __shfl_xor(lsum, 16);
        lsum += __shfl_xor(lsum, 32);
        if (g == 0) atomicAdd(&l_acc[head * LL + qbase + c], lsum);
#pragma unroll
        for (int r = 0; r < 4; r++) {
            int l = qbase + g * 4 + r;
            float* dst = ctx_acc + ((size_t)(b_ * LL + l)) * (HH * DD) + h * DD + c;
#pragma unroll
            for (int tt = 0; tt < 8; tt++)
                atomicAdd(dst + tt * 16, o[tt][r]);
        }
    }
}

// ctx_bf16 = f2bf(ctx_acc / l_acc[head][l])
__global__ __launch_bounds__(256) void norm_cast(const float* __restrict__ acc,
                                                 const float* __restrict__ l_acc,
                                                 u16* __restrict__ ctx) {
    int i = blockIdx.x * 256 + threadIdx.x;
    int e = i * 4;
    int bl = e >> 9;
    int col = e & 511;
    int b_ = bl >> 12, l = bl & 4095;
    int h = col >> 7;
    float inv = 1.f / l_acc[(b_ * HH + h) * LL + l];
    float4 v = *(const float4*)(acc + e);
    ushort4 o;
    o.x = f2bf(v.x * inv); o.y = f2bf(v.y * inv);
    o.z = f2bf(v.z * inv); o.w = f2bf(v.w * inv);
    *(ushort4*)(ctx + e) = o;
}

// y = ctx(8192x512) @ Wo(128x512)^T -> fp32 [B,L,128]
__global__ __launch_bounds__(256) void proj_out(const u16* __restrict__ ctx,
                                                const u16* __restrict__ wo,
                                                float* __restrict__ y) {
    int lane = threadIdx.x & 63;
    int w4   = threadIdx.x >> 6;
    int c = lane & 15, g = lane >> 4;
    int mt = blockIdx.x;
    int nt = blockIdx.y * 4 + w4;

    const u16* ap = ctx + (mt * 16 + c) * 512 + g * 8;
    const u16* bp = wo  + (nt * 16 + c) * 512 + g * 8;
    floatx4 acc = {0.f, 0.f, 0.f, 0.f};
#pragma unroll
    for (int kk = 0; kk < 16; kk++) {
        short8 a = *(const short8*)(ap + kk * 32);
        short8 b = *(const short8*)(bp + kk * 32);
        acc = __builtin_amdgcn_mfma_f32_16x16x32_bf16(a, b, acc, 0, 0, 0);
    }
#pragma unroll
    for (int r = 0; r < 4; r++) {
        y[(mt * 16 + g * 4 + r) * DD + nt * 16 + c] = acc[r];
    }
}

extern "C" void kernel_launch(void* const* d_in, const int* in_sizes, int n_in,
                              void* d_out, int out_size, void* d_ws, size_t ws_size,
                              hipStream_t stream) {
    const float* x  = (const float*)d_in[0];
    const float* Wq = (const float*)d_in[1];
    const float* Wk = (const float*)d_in[2];
    const float* Wv = (const float*)d_in[3];
    const float* Wo = (const float*)d_in[4];
    float* y = (float*)d_out;

    u16* ws  = (u16*)d_ws;
    u16* xb  = ws;
    u16* wqb = xb  + BB * LL * DD;
    u16* wkb = wqb + HH * DD * DD;
    u16* wvb = wkb + HH * DD * DD;
    u16* wob = wvb + HH * DD * DD;
    u16* Qb  = wob + DD * HH * DD;         // [B,H,L,128]
    u16* Kb  = Qb  + BB * HH * LL * DD;
    u16* Vt  = Kb  + BB * HH * LL * DD;    // [B,H,128,L]
    u16* ctx = Vt  + BB * HH * LL * DD;    // [B,L,512] bf16
    float* ctx_acc = (float*)(ctx + (size_t)BB * LL * HH * DD);  // fp32 [B,L,512]
    float* l_acc   = ctx_acc + (size_t)BB * LL * HH * DD;        // [B*H, L]

    // ctx_acc and l_acc are adjacent: one memset
    hipMemsetAsync(ctx_acc, 0, ((size_t)BB * LL * HH * DD + (size_t)BB * HH * LL) * 4, stream);

    cvt_all<<<dim3(1024, 5), 256, 0, stream>>>(x, Wq, Wk, Wv, Wo,
                                               xb, wqb, wkb, wvb, wob);
    proj_qkv<<<dim3(512, 8, 3), 256, 0, stream>>>(xb, wqb, wkb, wvb, Qb, Kb, Vt);
    flash_attn<<<dim3(640), 512, 0, stream>>>(Qb, Kb, Vt, ctx_acc, l_acc);
    norm_cast<<<dim3(4096), 256, 0, stream>>>(ctx_acc, l_acc, ctx);
    proj_out<<<dim3(512, 2), 256, 0, stream>>>(ctx, wob, y);
}

// Round 5
// 453.889 us; speedup vs baseline: 1.8021x; 1.8021x over previous
//
#include <hip/hip_runtime.h>

#define BB 2
#define LL 4096
#define DD 128
#define HH 4

typedef unsigned short u16;
typedef unsigned int u32;
typedef __attribute__((ext_vector_type(8))) short short8;   // 8 bf16
typedef __attribute__((ext_vector_type(4))) float floatx4;

__device__ __forceinline__ u16 f2bf(float f) {
    union { float f; u32 u; } v; v.f = f;
    return (u16)((v.u + 0x7fffu + ((v.u >> 16) & 1u)) >> 16);
}

__global__ __launch_bounds__(256) void cvt_all(const float* __restrict__ x,
                                               const float* __restrict__ wq,
                                               const float* __restrict__ wk,
                                               const float* __restrict__ wv,
                                               const float* __restrict__ wo,
                                               u16* xb, u16* wqb, u16* wkb,
                                               u16* wvb, u16* wob) {
    int z = blockIdx.y;
    const float* src; u16* dst; int n;
    if      (z == 0) { src = x;  dst = xb;  n = BB * LL * DD; }
    else if (z == 1) { src = wq; dst = wqb; n = HH * DD * DD; }
    else if (z == 2) { src = wk; dst = wkb; n = HH * DD * DD; }
    else if (z == 3) { src = wv; dst = wvb; n = HH * DD * DD; }
    else             { src = wo; dst = wob; n = DD * HH * DD; }
    int i = (blockIdx.x * 256 + threadIdx.x) * 4;
    if (i >= n) return;
    float4 v = *(const float4*)(src + i);
    ushort4 o;
    o.x = f2bf(v.x); o.y = f2bf(v.y); o.z = f2bf(v.z); o.w = f2bf(v.w);
    *(ushort4*)(dst + i) = o;
}

// Fused QKV projection. z=0: Q row-major [B,H,L,E]; z=1: K row-major;
// z=2: V transposed [B,H,E,L] via MFMA operand swap.
__global__ __launch_bounds__(256) void proj_qkv(const u16* __restrict__ xb,
                                                const u16* __restrict__ wqb,
                                                const u16* __restrict__ wkb,
                                                const u16* __restrict__ wvb,
                                                u16* __restrict__ Qb,
                                                u16* __restrict__ Kb,
                                                u16* __restrict__ Vt) {
    int z = blockIdx.z;
    const u16* w = (z == 0) ? wqb : (z == 1) ? wkb : wvb;
    u16* out     = (z == 0) ? Qb  : (z == 1) ? Kb  : Vt;
    int lane = threadIdx.x & 63;
    int w4   = threadIdx.x >> 6;
    int c = lane & 15, g = lane >> 4;
    int mt = blockIdx.x;
    int nt = blockIdx.y * 4 + w4;

    const u16* xp = xb + (mt * 16 + c) * DD + g * 8;
    const u16* wp = w  + (nt * 16 + c) * DD + g * 8;

    floatx4 acc = {0.f, 0.f, 0.f, 0.f};
    if (z < 2) {
#pragma unroll
        for (int kk = 0; kk < 4; kk++) {
            short8 a = *(const short8*)(xp + kk * 32);
            short8 b = *(const short8*)(wp + kk * 32);
            acc = __builtin_amdgcn_mfma_f32_16x16x32_bf16(a, b, acc, 0, 0, 0);
        }
        int n = nt * 16 + c;
        int h = n >> 7, e = n & 127;
#pragma unroll
        for (int r = 0; r < 4; r++) {
            int m = mt * 16 + g * 4 + r;
            int b_ = m >> 12, l = m & 4095;
            out[((b_ * HH + h) * LL + l) * DD + e] = f2bf(acc[r]);
        }
    } else {
#pragma unroll
        for (int kk = 0; kk < 4; kk++) {
            short8 a = *(const short8*)(wp + kk * 32);
            short8 b = *(const short8*)(xp + kk * 32);
            acc = __builtin_amdgcn_mfma_f32_16x16x32_bf16(a, b, acc, 0, 0, 0);
        }
        int lg = mt * 16 + c;
        int b_ = lg >> 12, l = lg & 4095;
        int n0 = nt * 16;
        int h = n0 >> 7, e0 = n0 & 127;
#pragma unroll
        for (int r = 0; r < 4; r++) {
            out[((b_ * HH + h) * DD + e0 + g * 4 + r) * LL + l] = f2bf(acc[r]);
        }
    }
}

// Flash attention, causal, no-max softmax, additive chunk combine.
// Block = 4 waves = 64 q rows of one head; waves share identical K/V tile
// addresses each step (MSHR merge + L1 dedup), barrier-converged.
// K chunked in 1024-key slabs; full chunks dispatched first.
// launch_bounds(256,4): VGPR cap 128 vs ~80 needed (R3: 76) — NO SPILL.
__global__ __launch_bounds__(256, 4) void flash_attn(const u16* __restrict__ Q,
                                                     const u16* __restrict__ K,
                                                     const u16* __restrict__ Vt,
                                                     float* __restrict__ ctx_acc,
                                                     float* __restrict__ l_acc) {
    int lane = threadIdx.x & 63;
    int wv   = threadIdx.x >> 6;          // 0..3
    int c = lane & 15, g = lane >> 4;

    int bid  = blockIdx.x;
    int head = bid & 7;                   // b*H + h
    int i    = bid >> 3;                  // 0..159
    int t, ch;
    if      (i < 48) { t = 48 + i / 3;          ch = i % 3; }       // 32-step full
    else if (i < 80) { int f = i - 48; t = 32 + (f >> 1); ch = f & 1; }
    else if (i < 96) { t = 16 + (i - 80);       ch = 0; }
    else { int d = i - 96; int r = 15 - (d >> 2); ch = d & 3; t = ch * 16 + r; } // diag, desc size

    int b_ = head >> 2, h = head & 3;
    int kstart = ch << 10;
    int kend   = min(t * 64 + 64, kstart + 1024);
    int nsteps = (kend - kstart + 31) >> 5;        // block-uniform

    int qbase = t * 64 + wv * 16;
    int q_c   = qbase + c;
    // wave's personal active-step count (kstart <= qbase always here)
    int my_steps = min(nsteps, ((qbase + 15 - kstart) >> 5) + 1);

    // Q as B-fragment (n = c = q-row, k = g*8..)
    const u16* qp = Q + ((size_t)head * LL + qbase + c) * DD + g * 8;
    short8 bq[4];
#pragma unroll
    for (int kk = 0; kk < 4; kk++) bq[kk] = *(const short8*)(qp + kk * 32);

    const u16* kp  = K  + ((size_t)head * LL + kstart + c) * DD + g * 8;
    const u16* vp0 = Vt + ((size_t)head * DD + c) * LL + kstart + g * 8;

    floatx4 o[8];
#pragma unroll
    for (int tt = 0; tt < 8; tt++) o[tt] = (floatx4){0.f, 0.f, 0.f, 0.f};
    float lsum = 0.f;

    int s0 = c + (((g << 1) & 3) << 4);
    int s1 = c + ((((g << 1) | 1) & 3) << 4);
    bool hi = (g >= 2);

    // preload K for step 0
    short8 ka[8];
#pragma unroll
    for (int kk = 0; kk < 4; kk++) {
        ka[kk]     = *(const short8*)(kp + kk * 32);
        ka[4 + kk] = *(const short8*)(kp + 16 * DD + kk * 32);
    }
    kp += 32 * DD;

    for (int j = 0; j < nsteps; ++j) {
        __syncthreads();                  // keep 4 waves converged for dedup
        if (j < my_steps) {
            int kb = kstart + (j << 5);
            // V tile for this step (same addrs across all 4 waves)
            short8 vb[8];
#pragma unroll
            for (int tt = 0; tt < 8; tt++)
                vb[tt] = *(const short8*)(vp0 + (size_t)tt * 16 * LL + (j << 5));

            // S^T = K · Q^T
            floatx4 st0 = {0.f,0.f,0.f,0.f}, st1 = {0.f,0.f,0.f,0.f};
#pragma unroll
            for (int kk = 0; kk < 4; kk++) {
                st0 = __builtin_amdgcn_mfma_f32_16x16x32_bf16(ka[kk],     bq[kk], st0, 0, 0, 0);
                st1 = __builtin_amdgcn_mfma_f32_16x16x32_bf16(ka[4 + kk], bq[kk], st1, 0, 0, 0);
            }
            // prefetch next K tile
            if (j + 1 < my_steps) {
#pragma unroll
                for (int kk = 0; kk < 4; kk++) {
                    ka[kk]     = *(const short8*)(kp + kk * 32);
                    ka[4 + kk] = *(const short8*)(kp + 16 * DD + kk * 32);
                }
                kp += 32 * DD;
            }

            // exp (no max subtraction); mask only near the diagonal
            float p[8];
            if (kb + 31 > qbase) {
#pragma unroll
                for (int r = 0; r < 4; r++) {
                    int k0 = kb + g * 4 + r;
                    p[r]     = (k0      <= q_c) ? st0[r] : -INFINITY;
                    p[4 + r] = (k0 + 16 <= q_c) ? st1[r] : -INFINITY;
                }
            } else {
#pragma unroll
                for (int r = 0; r < 4; r++) { p[r] = st0[r]; p[4 + r] = st1[r]; }
            }
#pragma unroll
            for (int i2 = 0; i2 < 8; i2++) { p[i2] = __expf(p[i2]); lsum += p[i2]; }

            // pack P -> bf16 pairs, exchange into PV A-fragment
            u32 pk00 = (u32)f2bf(p[0]) | ((u32)f2bf(p[1]) << 16);
            u32 pk01 = (u32)f2bf(p[2]) | ((u32)f2bf(p[3]) << 16);
            u32 pk10 = (u32)f2bf(p[4]) | ((u32)f2bf(p[5]) << 16);
            u32 pk11 = (u32)f2bf(p[6]) | ((u32)f2bf(p[7]) << 16);
            u32 x00 = (u32)__shfl((int)pk00, s0), x10 = (u32)__shfl((int)pk10, s0);
            u32 x01 = (u32)__shfl((int)pk01, s0), x11 = (u32)__shfl((int)pk11, s0);
            u32 y00 = (u32)__shfl((int)pk00, s1), y10 = (u32)__shfl((int)pk10, s1);
            u32 y01 = (u32)__shfl((int)pk01, s1), y11 = (u32)__shfl((int)pk11, s1);
            union { short8 s; u32 u[4]; } au;
            au.u[0] = hi ? x10 : x00;
            au.u[1] = hi ? x11 : x01;
            au.u[2] = hi ? y10 : y00;
            au.u[3] = hi ? y11 : y01;

#pragma unroll
            for (int tt = 0; tt < 8; tt++)
                o[tt] = __builtin_amdgcn_mfma_f32_16x16x32_bf16(au.s, vb[tt], o[tt], 0, 0, 0);
        }
    }

    lsum += __shfl_xor(lsum, 16);
    lsum += __shfl_xor(lsum, 32);
    if (g == 0) atomicAdd(&l_acc[head * LL + qbase + c], lsum);
#pragma unroll
    for (int r = 0; r < 4; r++) {
        int l = qbase + g * 4 + r;
        float* dst = ctx_acc + ((size_t)(b_ * LL + l)) * (HH * DD) + h * DD + c;
#pragma unroll
        for (int tt = 0; tt < 8; tt++)
            atomicAdd(dst + tt * 16, o[tt][r]);
    }
}

// ctx_bf16 = f2bf(ctx_acc / l_acc[head][l])
__global__ __launch_bounds__(256) void norm_cast(const float* __restrict__ acc,
                                                 const float* __restrict__ l_acc,
                                                 u16* __restrict__ ctx) {
    int i = blockIdx.x * 256 + threadIdx.x;
    int e = i * 4;
    int bl = e >> 9;
    int col = e & 511;
    int b_ = bl >> 12, l = bl & 4095;
    int h = col >> 7;
    float inv = 1.f / l_acc[(b_ * HH + h) * LL + l];
    float4 v = *(const float4*)(acc + e);
    ushort4 o;
    o.x = f2bf(v.x * inv); o.y = f2bf(v.y * inv);
    o.z = f2bf(v.z * inv); o.w = f2bf(v.w * inv);
    *(ushort4*)(ctx + e) = o;
}

// y = ctx(8192x512) @ Wo(128x512)^T -> fp32 [B,L,128]
__global__ __launch_bounds__(256) void proj_out(const u16* __restrict__ ctx,
                                                const u16* __restrict__ wo,
                                                float* __restrict__ y) {
    int lane = threadIdx.x & 63;
    int w4   = threadIdx.x >> 6;
    int c = lane & 15, g = lane >> 4;
    int mt = blockIdx.x;
    int nt = blockIdx.y * 4 + w4;

    const u16* ap = ctx + (mt * 16 + c) * 512 + g * 8;
    const u16* bp = wo  + (nt * 16 + c) * 512 + g * 8;
    floatx4 acc = {0.f, 0.f, 0.f, 0.f};
#pragma unroll
    for (int kk = 0; kk < 16; kk++) {
        short8 a = *(const short8*)(ap + kk * 32);
        short8 b = *(const short8*)(bp + kk * 32);
        acc = __builtin_amdgcn_mfma_f32_16x16x32_bf16(a, b, acc, 0, 0, 0);
    }
#pragma unroll
    for (int r = 0; r < 4; r++) {
        y[(mt * 16 + g * 4 + r) * DD + nt * 16 + c] = acc[r];
    }
}

extern "C" void kernel_launch(void* const* d_in, const int* in_sizes, int n_in,
                              void* d_out, int out_size, void* d_ws, size_t ws_size,
                              hipStream_t stream) {
    const float* x  = (const float*)d_in[0];
    const float* Wq = (const float*)d_in[1];
    const float* Wk = (const float*)d_in[2];
    const float* Wv = (const float*)d_in[3];
    const float* Wo = (const float*)d_in[4];
    float* y = (float*)d_out;

    u16* ws  = (u16*)d_ws;
    u16* xb  = ws;
    u16* wqb = xb  + BB * LL * DD;
    u16* wkb = wqb + HH * DD * DD;
    u16* wvb = wkb + HH * DD * DD;
    u16* wob = wvb + HH * DD * DD;
    u16* Qb  = wob + DD * HH * DD;         // [B,H,L,128]
    u16* Kb  = Qb  + BB * HH * LL * DD;
    u16* Vt  = Kb  + BB * HH * LL * DD;    // [B,H,128,L]
    u16* ctx = Vt  + BB * HH * LL * DD;    // [B,L,512] bf16
    float* ctx_acc = (float*)(ctx + (size_t)BB * LL * HH * DD);  // fp32 [B,L,512]
    float* l_acc   = ctx_acc + (size_t)BB * LL * HH * DD;        // [B*H, L]

    hipMemsetAsync(ctx_acc, 0, ((size_t)BB * LL * HH * DD + (size_t)BB * HH * LL) * 4, stream);

    cvt_all<<<dim3(1024, 5), 256, 0, stream>>>(x, Wq, Wk, Wv, Wo,
                                               xb, wqb, wkb, wvb, wob);
    proj_qkv<<<dim3(512, 8, 3), 256, 0, stream>>>(xb, wqb, wkb, wvb, Qb, Kb, Vt);
    flash_attn<<<dim3(1280), 256, 0, stream>>>(Qb, Kb, Vt, ctx_acc, l_acc);
    norm_cast<<<dim3(4096), 256, 0, stream>>>(ctx_acc, l_acc, ctx);
    proj_out<<<dim3(512, 2), 256, 0, stream>>>(ctx, wob, y);
}

// Round 7
// 214.595 us; speedup vs baseline: 3.8116x; 2.1151x over previous
//
#include <hip/hip_runtime.h>

#define BB 2
#define LL 4096
#define DD 128
#define HH 4

typedef unsigned short u16;
typedef unsigned int u32;
typedef __attribute__((ext_vector_type(8))) short short8;   // 8 bf16
typedef __attribute__((ext_vector_type(4))) float floatx4;

union PFrag { short8 s; u32 u[4]; };

__device__ __forceinline__ u16 f2bf(float f) {
    union { float f; u32 u; } v; v.f = f;
    return (u16)((v.u + 0x7fffu + ((v.u >> 16) & 1u)) >> 16);
}

// async global->LDS, 16B per lane; lds dest must be wave-uniform base
__device__ __forceinline__ void gld16(const u16* g, u16* l) {
    __builtin_amdgcn_global_load_lds((const __attribute__((address_space(1))) void*)g,
                                     (__attribute__((address_space(3))) void*)l, 16, 0, 0);
}

// slot prefix: number of full (non-diagonal) chunks for tiles t' < t (valid t>=8)
__device__ __forceinline__ int pfx(int t) {
    return (t < 16) ? (t - 8) : (t < 24) ? 8 + (t - 16) * 2 : 24 + (t - 24) * 3;
}

__global__ __launch_bounds__(256) void cvt_all(const float* __restrict__ x,
                                               const float* __restrict__ wq,
                                               const float* __restrict__ wk,
                                               const float* __restrict__ wv,
                                               const float* __restrict__ wo,
                                               u16* xb, u16* wqb, u16* wkb,
                                               u16* wvb, u16* wob) {
    int z = blockIdx.y;
    const float* src; u16* dst; int n;
    if      (z == 0) { src = x;  dst = xb;  n = BB * LL * DD; }
    else if (z == 1) { src = wq; dst = wqb; n = HH * DD * DD; }
    else if (z == 2) { src = wk; dst = wkb; n = HH * DD * DD; }
    else if (z == 3) { src = wv; dst = wvb; n = HH * DD * DD; }
    else             { src = wo; dst = wob; n = DD * HH * DD; }
    int i = (blockIdx.x * 256 + threadIdx.x) * 4;
    if (i >= n) return;
    float4 v = *(const float4*)(src + i);
    ushort4 o;
    o.x = f2bf(v.x); o.y = f2bf(v.y); o.z = f2bf(v.z); o.w = f2bf(v.w);
    *(ushort4*)(dst + i) = o;
}

// Fused QKV projection. z=0: Q row-major [B,H,L,E]; z=1: K row-major;
// z=2: V transposed [B,H,E,L] via MFMA operand swap.
__global__ __launch_bounds__(256) void proj_qkv(const u16* __restrict__ xb,
                                                const u16* __restrict__ wqb,
                                                const u16* __restrict__ wkb,
                                                const u16* __restrict__ wvb,
                                                u16* __restrict__ Qb,
                                                u16* __restrict__ Kb,
                                                u16* __restrict__ Vt) {
    int z = blockIdx.z;
    const u16* w = (z == 0) ? wqb : (z == 1) ? wkb : wvb;
    u16* out     = (z == 0) ? Qb  : (z == 1) ? Kb  : Vt;
    int lane = threadIdx.x & 63;
    int w4   = threadIdx.x >> 6;
    int c = lane & 15, g = lane >> 4;
    int mt = blockIdx.x;
    int nt = blockIdx.y * 4 + w4;

    const u16* xp = xb + (mt * 16 + c) * DD + g * 8;
    const u16* wp = w  + (nt * 16 + c) * DD + g * 8;

    floatx4 acc = {0.f, 0.f, 0.f, 0.f};
    if (z < 2) {
#pragma unroll
        for (int kk = 0; kk < 4; kk++) {
            short8 a = *(const short8*)(xp + kk * 32);
            short8 b = *(const short8*)(wp + kk * 32);
            acc = __builtin_amdgcn_mfma_f32_16x16x32_bf16(a, b, acc, 0, 0, 0);
        }
        int n = nt * 16 + c;
        int h = n >> 7, e = n & 127;
#pragma unroll
        for (int r = 0; r < 4; r++) {
            int m = mt * 16 + g * 4 + r;
            int b_ = m >> 12, l = m & 4095;
            out[((b_ * HH + h) * LL + l) * DD + e] = f2bf(acc[r]);
        }
    } else {
#pragma unroll
        for (int kk = 0; kk < 4; kk++) {
            short8 a = *(const short8*)(wp + kk * 32);
            short8 b = *(const short8*)(xp + kk * 32);
            acc = __builtin_amdgcn_mfma_f32_16x16x32_bf16(a, b, acc, 0, 0, 0);
        }
        int lg = mt * 16 + c;
        int b_ = lg >> 12, l = lg & 4095;
        int n0 = nt * 16;
        int h = n0 >> 7, e0 = n0 & 127;
#pragma unroll
        for (int r = 0; r < 4; r++) {
            out[((b_ * HH + h) * DD + e0 + g * 4 + r) * LL + l] = f2bf(acc[r]);
        }
    }
}

// Flash attention, causal, no-max softmax. Block = 4 waves x 32 q-rows = 128
// q-rows of one head, over one 1024-key chunk (<=32 steps of 32 keys).
// K/V tiles staged via async global_load_lds, double-buffered; K tile
// XOR-swizzled for conflict-free ds_read_b128. Each block writes a private
// fp32 partial tile (no ctx atomics); diagonal chunk writes the base tile.
__global__ __launch_bounds__(256) void flash_attn(const u16* __restrict__ Q,
                                                  const u16* __restrict__ K,
                                                  const u16* __restrict__ Vt,
                                                  float* __restrict__ ctx_base,
                                                  float* __restrict__ slots,
                                                  float* __restrict__ l_acc) {
    __shared__ __align__(16) u16 Kls[2][32 * 128];   // rows k (256B), swizzled
    __shared__ __align__(16) u16 Vls[2][128 * 32];   // rows e (64B)

    int lane = threadIdx.x & 63;
    int w    = threadIdx.x >> 6;          // 0..3
    int c = lane & 15, g = lane >> 4;

    int bid  = blockIdx.x;
    int head = bid & 7;                   // b*H + h
    int i    = bid >> 3;                  // 0..79
    int t, ch;
    if      (i < 8)  { t = 8 + i; ch = 0; }
    else if (i < 24) { int f = i - 8;  t = 16 + (f >> 1); ch = f & 1; }
    else if (i < 48) { int f = i - 24; t = 24 + f / 3;    ch = f % 3; }
    else             { int d = i - 48; t = ((d & 3) << 3) + (7 - (d >> 2)); ch = d & 3; }

    int kstart = ch << 10;
    int kend   = min(t * 128 + 128, kstart + 1024);
    int nsteps = (kend - kstart) >> 5;    // exact multiple

    int qb = t * 128 + w * 32;
    int my_steps = min(nsteps, ((qb + 31 - kstart) >> 5) + 1);

    // Q B-fragments for two q-halves (n=c=q-row, k=g*8..)
    short8 bq0[4], bq1[4];
    {
        const u16* qp0 = Q + ((size_t)head * LL + qb + c) * DD + g * 8;
        const u16* qp1 = qp0 + 16 * DD;
#pragma unroll
        for (int kk = 0; kk < 4; kk++) {
            bq0[kk] = *(const short8*)(qp0 + kk * 32);
            bq1[kk] = *(const short8*)(qp1 + kk * 32);
        }
    }

    floatx4 o0[8], o1[8];
#pragma unroll
    for (int tt = 0; tt < 8; tt++) {
        o0[tt] = (floatx4){0.f, 0.f, 0.f, 0.f};
        o1[tt] = (floatx4){0.f, 0.f, 0.f, 0.f};
    }
    float lsum0 = 0.f, lsum1 = 0.f;

    int s0 = c + (((g << 1) & 3) << 4);
    int s1 = c + ((((g << 1) | 1) & 3) << 4);
    bool hi = (g >= 2);

    const u16* Kg0 = K  + ((size_t)head * LL + kstart) * DD;
    const u16* Vg0 = Vt + (size_t)head * DD * LL + kstart;

    // DMA stage for step s into buffer s&1 (all waves participate)
    int q0 = w * 64 + lane;               // chunk id, this wave issue 0
    int r0 = q0 >> 4, cc0 = (q0 & 15) ^ (r0 & 15);
    int r1 = r0 + 16,  cc1 = (q0 & 15) ^ (r1 & 15);
    int e0 = q0 >> 2, c40 = (q0 & 3) * 8;
    int e1 = e0 + 64;

#define STAGE(s) {                                                          \
        int buf_ = (s) & 1; int kb_ = (s) << 5;                             \
        const u16* Kg = Kg0 + (size_t)kb_ * DD;                             \
        const u16* Vg = Vg0 + kb_;                                          \
        gld16(Kg + r0 * DD + cc0 * 8, &Kls[buf_][w * 512]);                 \
        gld16(Kg + r1 * DD + cc1 * 8, &Kls[buf_][2048 + w * 512]);          \
        gld16(Vg + (size_t)e0 * LL + c40, &Vls[buf_][w * 512]);             \
        gld16(Vg + (size_t)e1 * LL + c40, &Vls[buf_][2048 + w * 512]);      \
    }

    STAGE(0);

    for (int j = 0; j < nsteps; ++j) {
        __syncthreads();                  // drains DMA j (issued 1 step ago)
        if (j + 1 < nsteps) STAGE(j + 1);
        if (j < my_steps) {
            int kb = kstart + (j << 5);
            const u16* Kb_ = &Kls[j & 1][0];
            const u16* Vb_ = &Vls[j & 1][0];

            // S^T = K·Q^T for both q-halves
            floatx4 st00 = {0,0,0,0}, st01 = {0,0,0,0};   // qh0: khalf0/1
            floatx4 st10 = {0,0,0,0}, st11 = {0,0,0,0};   // qh1
            {
                short8 ka[4];
#pragma unroll
                for (int kk = 0; kk < 4; kk++)
                    ka[kk] = *(const short8*)(Kb_ + c * 128 + (((g + 4 * kk) ^ c)) * 8);
#pragma unroll
                for (int kk = 0; kk < 4; kk++) {
                    st00 = __builtin_amdgcn_mfma_f32_16x16x32_bf16(ka[kk], bq0[kk], st00, 0, 0, 0);
                    st10 = __builtin_amdgcn_mfma_f32_16x16x32_bf16(ka[kk], bq1[kk], st10, 0, 0, 0);
                }
#pragma unroll
                for (int kk = 0; kk < 4; kk++)
                    ka[kk] = *(const short8*)(Kb_ + (16 + c) * 128 + (((g + 4 * kk) ^ c)) * 8);
#pragma unroll
                for (int kk = 0; kk < 4; kk++) {
                    st01 = __builtin_amdgcn_mfma_f32_16x16x32_bf16(ka[kk], bq0[kk], st01, 0, 0, 0);
                    st11 = __builtin_amdgcn_mfma_f32_16x16x32_bf16(ka[kk], bq1[kk], st11, 0, 0, 0);
                }
            }

            // softmax (no max) + pack + exchange, per q-half
            PFrag au0, au1;
#pragma unroll
            for (int qh = 0; qh < 2; qh++) {
                floatx4 sa = qh ? st10 : st00;
                floatx4 sb = qh ? st11 : st01;
                int qbh = qb + qh * 16;
                float p[8];
                if (kb + 31 > qbh) {
                    int q_c = qbh + c;
#pragma unroll
                    for (int r = 0; r < 4; r++) {
                        int k0 = kb + g * 4 + r;
                        p[r]     = (k0      <= q_c) ? sa[r] : -INFINITY;
                        p[4 + r] = (k0 + 16 <= q_c) ? sb[r] : -INFINITY;
                    }
                } else {
#pragma unroll
                    for (int r = 0; r < 4; r++) { p[r] = sa[r]; p[4 + r] = sb[r]; }
                }
                float ls = 0.f;
#pragma unroll
                for (int i2 = 0; i2 < 8; i2++) { p[i2] = __expf(p[i2]); ls += p[i2]; }
                if (qh) lsum1 += ls; else lsum0 += ls;

                u32 pk00 = (u32)f2bf(p[0]) | ((u32)f2bf(p[1]) << 16);
                u32 pk01 = (u32)f2bf(p[2]) | ((u32)f2bf(p[3]) << 16);
                u32 pk10 = (u32)f2bf(p[4]) | ((u32)f2bf(p[5]) << 16);
                u32 pk11 = (u32)f2bf(p[6]) | ((u32)f2bf(p[7]) << 16);
                u32 x00 = (u32)__shfl((int)pk00, s0), x10 = (u32)__shfl((int)pk10, s0);
                u32 x01 = (u32)__shfl((int)pk01, s0), x11 = (u32)__shfl((int)pk11, s0);
                u32 y00 = (u32)__shfl((int)pk00, s1), y10 = (u32)__shfl((int)pk10, s1);
                u32 y01 = (u32)__shfl((int)pk01, s1), y11 = (u32)__shfl((int)pk11, s1);
                PFrag* au = qh ? &au1 : &au0;
                au->u[0] = hi ? x10 : x00;
                au->u[1] = hi ? x11 : x01;
                au->u[2] = hi ? y10 : y00;
                au->u[3] = hi ? y11 : y01;
            }

            // PV from LDS V tile (rows e, 64B)
#pragma unroll
            for (int tt = 0; tt < 8; tt++) {
                short8 vb = *(const short8*)(Vb_ + (tt * 16 + c) * 32 + g * 8);
                o0[tt] = __builtin_amdgcn_mfma_f32_16x16x32_bf16(au0.s, vb, o0[tt], 0, 0, 0);
                o1[tt] = __builtin_amdgcn_mfma_f32_16x16x32_bf16(au1.s, vb, o1[tt], 0, 0, 0);
            }
        }
    }
#undef STAGE

    // l partials (cheap atomics)
    lsum0 += __shfl_xor(lsum0, 16); lsum0 += __shfl_xor(lsum0, 32);
    lsum1 += __shfl_xor(lsum1, 16); lsum1 += __shfl_xor(lsum1, 32);
    if (g == 0) {
        atomicAdd(&l_acc[head * LL + qb + c],      lsum0);
        atomicAdd(&l_acc[head * LL + qb + 16 + c], lsum1);
    }

    // O partial store (plain stores, one owner per element)
    bool diag = (ch == (t >> 3));
    float* dst0 = diag ? ctx_base + ((size_t)head * LL + t * 128) * 128
                       : slots + (size_t)(head * 48 + pfx(t) + ch) * 16384;
    dst0 += (size_t)(w * 32) * 128;
#pragma unroll
    for (int r = 0; r < 4; r++) {
        float* d0 = dst0 + (g * 4 + r) * 128 + c;
        float* d1 = d0 + 16 * 128;
#pragma unroll
        for (int tt = 0; tt < 8; tt++) {
            d0[tt * 16] = o0[tt][r];
            d1[tt * 16] = o1[tt][r];
        }
    }
}

// ctx_bf16 = f2bf((base + sum slots) / l)
__global__ __launch_bounds__(256) void norm_cast(const float* __restrict__ base,
                                                 const float* __restrict__ slots,
                                                 const float* __restrict__ l_acc,
                                                 u16* __restrict__ ctx) {
    int i = blockIdx.x * 256 + threadIdx.x;
    int e4 = i * 4;
    int col = e4 & 511;
    int bl  = e4 >> 9;
    int b_ = bl >> 12, l = bl & 4095;
    int h = col >> 7, d = col & 127;
    int head = b_ * HH + h;
    int t = l >> 7;
    int nx = t >> 3;

    float4 v = *(const float4*)(base + ((size_t)head * LL + l) * 128 + d);
    if (nx > 0) {
        int sb = head * 48 + pfx(t);
        for (int x = 0; x < nx; x++) {
            float4 sv = *(const float4*)(slots + (size_t)(sb + x) * 16384 + (l & 127) * 128 + d);
            v.x += sv.x; v.y += sv.y; v.z += sv.z; v.w += sv.w;
        }
    }
    float inv = 1.f / l_acc[head * LL + l];
    ushort4 o;
    o.x = f2bf(v.x * inv); o.y = f2bf(v.y * inv);
    o.z = f2bf(v.z * inv); o.w = f2bf(v.w * inv);
    *(ushort4*)(ctx + e4) = o;
}

// y = ctx(8192x512) @ Wo(128x512)^T -> fp32 [B,L,128]
__global__ __launch_bounds__(256) void proj_out(const u16* __restrict__ ctx,
                                                const u16* __restrict__ wo,
                                                float* __restrict__ y) {
    int lane = threadIdx.x & 63;
    int w4   = threadIdx.x >> 6;
    int c = lane & 15, g = lane >> 4;
    int mt = blockIdx.x;
    int nt = blockIdx.y * 4 + w4;

    const u16* ap = ctx + (mt * 16 + c) * 512 + g * 8;
    const u16* bp = wo  + (nt * 16 + c) * 512 + g * 8;
    floatx4 acc = {0.f, 0.f, 0.f, 0.f};
#pragma unroll
    for (int kk = 0; kk < 16; kk++) {
        short8 a = *(const short8*)(ap + kk * 32);
        short8 b = *(const short8*)(bp + kk * 32);
        acc = __builtin_amdgcn_mfma_f32_16x16x32_bf16(a, b, acc, 0, 0, 0);
    }
#pragma unroll
    for (int r = 0; r < 4; r++) {
        y[(mt * 16 + g * 4 + r) * DD + nt * 16 + c] = acc[r];
    }
}

extern "C" void kernel_launch(void* const* d_in, const int* in_sizes, int n_in,
                              void* d_out, int out_size, void* d_ws, size_t ws_size,
                              hipStream_t stream) {
    const float* x  = (const float*)d_in[0];
    const float* Wq = (const float*)d_in[1];
    const float* Wk = (const float*)d_in[2];
    const float* Wv = (const float*)d_in[3];
    const float* Wo = (const float*)d_in[4];
    float* y = (float*)d_out;

    u16* ws  = (u16*)d_ws;
    u16* xb  = ws;                          // 1,048,576
    u16* wqb = xb  + BB * LL * DD;          // 65,536 each
    u16* wkb = wqb + HH * DD * DD;
    u16* wvb = wkb + HH * DD * DD;
    u16* wob = wvb + HH * DD * DD;
    u16* Qb  = wob + DD * HH * DD;          // [B,H,L,128]
    u16* Kb  = Qb  + BB * HH * LL * DD;
    u16* Vt  = Kb  + BB * HH * LL * DD;     // [B,H,128,L]
    u16* ctx = Vt  + BB * HH * LL * DD;     // [B,L,512] bf16
    float* ctx_base = (float*)(ctx + (size_t)BB * LL * HH * DD);   // [8][L][128]
    float* slots    = ctx_base + (size_t)8 * LL * 128;             // 384 x 16384
    float* l_acc    = slots + (size_t)384 * 16384;                 // [8][L]

    (void)hipMemsetAsync(l_acc, 0, (size_t)8 * LL * 4, stream);

    cvt_all<<<dim3(1024, 5), 256, 0, stream>>>(x, Wq, Wk, Wv, Wo,
                                               xb, wqb, wkb, wvb, wob);
    proj_qkv<<<dim3(512, 8, 3), 256, 0, stream>>>(xb, wqb, wkb, wvb, Qb, Kb, Vt);
    flash_attn<<<dim3(640), 256, 0, stream>>>(Qb, Kb, Vt, ctx_base, slots, l_acc);
    norm_cast<<<dim3(4096), 256, 0, stream>>>(ctx_base, slots, l_acc, ctx);
    proj_out<<<dim3(512, 2), 256, 0, stream>>>(ctx, wob, y);
}

// Round 8
// 171.062 us; speedup vs baseline: 4.7816x; 1.2545x over previous
//
#include <hip/hip_runtime.h>

#define BB 2
#define LL 4096
#define DD 128
#define HH 4

typedef unsigned short u16;
typedef unsigned int u32;
typedef __attribute__((ext_vector_type(8))) short short8;   // 8 bf16
typedef __attribute__((ext_vector_type(4))) float floatx4;

union PFrag { short8 s; u32 u[4]; };

__device__ __forceinline__ u16 f2bf(float f) {
    union { float f; u32 u; } v; v.f = f;
    return (u16)((v.u + 0x7fffu + ((v.u >> 16) & 1u)) >> 16);
}

// async global->LDS, 16B per lane; lds dest must be wave-uniform base
__device__ __forceinline__ void gld16(const u16* g, u16* l) {
    __builtin_amdgcn_global_load_lds((const __attribute__((address_space(1))) void*)g,
                                     (__attribute__((address_space(3))) void*)l, 16, 0, 0);
}

// slot prefix: number of full (non-diagonal) chunks for tiles t' < t (valid t>=8)
__device__ __forceinline__ int pfx(int t) {
    return (t < 16) ? (t - 8) : (t < 24) ? 8 + (t - 16) * 2 : 24 + (t - 24) * 3;
}

// z=0: x, z=1..4: weights, z=5: zero l_acc
__global__ __launch_bounds__(256) void cvt_all(const float* __restrict__ x,
                                               const float* __restrict__ wq,
                                               const float* __restrict__ wk,
                                               const float* __restrict__ wv,
                                               const float* __restrict__ wo,
                                               u16* xb, u16* wqb, u16* wkb,
                                               u16* wvb, u16* wob,
                                               float* l_acc) {
    int z = blockIdx.y;
    if (z == 5) {
        int i = (blockIdx.x * 256 + threadIdx.x) * 4;
        if (i < 8 * LL) *(float4*)(l_acc + i) = (float4){0.f, 0.f, 0.f, 0.f};
        return;
    }
    const float* src; u16* dst; int n;
    if      (z == 0) { src = x;  dst = xb;  n = BB * LL * DD; }
    else if (z == 1) { src = wq; dst = wqb; n = HH * DD * DD; }
    else if (z == 2) { src = wk; dst = wkb; n = HH * DD * DD; }
    else if (z == 3) { src = wv; dst = wvb; n = HH * DD * DD; }
    else             { src = wo; dst = wob; n = DD * HH * DD; }
    int i = (blockIdx.x * 256 + threadIdx.x) * 4;
    if (i >= n) return;
    float4 v = *(const float4*)(src + i);
    ushort4 o;
    o.x = f2bf(v.x); o.y = f2bf(v.y); o.z = f2bf(v.z); o.w = f2bf(v.w);
    *(ushort4*)(dst + i) = o;
}

// Tiled QKV projection: 128x128 output tile per block, K=128 one-shot.
// grid (64 m-tiles, 12 n-tiles): nt>>2 = {Q,K,V}, nt&3 = head.
// V n-tiles swap MFMA operands to emit the transposed [B,H,E,L] tile.
// LDS tiles XOR-swizzled (16B chunk ^ row&15) -> conflict-free ds_read_b128.
__global__ __launch_bounds__(256) void proj_qkv(const u16* __restrict__ xb,
                                                const u16* __restrict__ wqb,
                                                const u16* __restrict__ wkb,
                                                const u16* __restrict__ wvb,
                                                u16* __restrict__ Qb,
                                                u16* __restrict__ Kb,
                                                u16* __restrict__ Vt) {
    __shared__ __align__(16) u16 At[128 * 128];
    __shared__ __align__(16) u16 Wt[128 * 128];
    int lane = threadIdx.x & 63;
    int w    = threadIdx.x >> 6;
    int c = lane & 15, g = lane >> 4;
    int mt = blockIdx.x;                  // 0..63
    int nt = blockIdx.y;                  // 0..11
    int z = nt >> 2, h = nt & 3;
    const u16* Wg = ((z == 0) ? wqb : (z == 1) ? wkb : wvb) + h * 128 * DD;
    const u16* Ag = xb + (size_t)mt * 128 * DD;

#pragma unroll
    for (int i = 0; i < 8; i++) {
        int row = i * 16 + w * 4 + (lane >> 4);
        int cc  = (lane & 15) ^ (row & 15);
        gld16(Ag + row * DD + cc * 8, &At[(i * 16 + w * 4) * 128]);
    }
#pragma unroll
    for (int i = 0; i < 8; i++) {
        int row = i * 16 + w * 4 + (lane >> 4);
        int cc  = (lane & 15) ^ (row & 15);
        gld16(Wg + row * DD + cc * 8, &Wt[(i * 16 + w * 4) * 128]);
    }
    __syncthreads();

    const u16* Abuf = (z < 2) ? At : Wt;   // a-operand rows (m)
    const u16* Bbuf = (z < 2) ? Wt : At;   // b-operand rows (n)

    floatx4 acc[2][8];
#pragma unroll
    for (int m2 = 0; m2 < 2; m2++)
#pragma unroll
        for (int n2 = 0; n2 < 8; n2++) acc[m2][n2] = (floatx4){0.f, 0.f, 0.f, 0.f};

#pragma unroll
    for (int kk = 0; kk < 4; kk++) {
        short8 a0, a1, bf[8];
        {
            int r0 = w * 32 + c;
            int r1 = r0 + 16;
            a0 = *(const short8*)(&Abuf[r0 * 128 + (((g + 4 * kk) ^ (r0 & 15)) * 8)]);
            a1 = *(const short8*)(&Abuf[r1 * 128 + (((g + 4 * kk) ^ (r1 & 15)) * 8)]);
        }
#pragma unroll
        for (int n2 = 0; n2 < 8; n2++) {
            int rn = n2 * 16 + c;
            bf[n2] = *(const short8*)(&Bbuf[rn * 128 + (((g + 4 * kk) ^ (rn & 15)) * 8)]);
        }
#pragma unroll
        for (int n2 = 0; n2 < 8; n2++) {
            acc[0][n2] = __builtin_amdgcn_mfma_f32_16x16x32_bf16(a0, bf[n2], acc[0][n2], 0, 0, 0);
            acc[1][n2] = __builtin_amdgcn_mfma_f32_16x16x32_bf16(a1, bf[n2], acc[1][n2], 0, 0, 0);
        }
    }

    if (z < 2) {
        u16* out = (z == 0) ? Qb : Kb;
#pragma unroll
        for (int m2 = 0; m2 < 2; m2++)
#pragma unroll
            for (int r = 0; r < 4; r++) {
                int lg = mt * 128 + w * 32 + m2 * 16 + g * 4 + r;
                int b_ = lg >> 12, l = lg & 4095;
                u16* op = out + ((size_t)(b_ * HH + h) * LL + l) * DD + c;
#pragma unroll
                for (int n2 = 0; n2 < 8; n2++) op[n2 * 16] = f2bf(acc[m2][n2][r]);
            }
    } else {
        int b_ = mt >> 5;
        int lbase = (mt & 31) * 128;
#pragma unroll
        for (int m2 = 0; m2 < 2; m2++)
#pragma unroll
            for (int r = 0; r < 4; r++) {
                int e = w * 32 + m2 * 16 + g * 4 + r;
                u16* op = Vt + ((size_t)(b_ * HH + h) * DD + e) * LL + lbase + c;
#pragma unroll
                for (int n2 = 0; n2 < 8; n2++) op[n2 * 16] = f2bf(acc[m2][n2][r]);
            }
    }
}

// Flash attention, causal, no-max softmax. Block = 4 waves x 32 q-rows = 128
// q-rows of one head, over one 1024-key chunk (<=32 steps of 32 keys).
// K/V tiles staged via async global_load_lds, double-buffered; K tile
// XOR-swizzled for conflict-free ds_read_b128. Each block writes a private
// fp32 partial tile (no ctx atomics); diagonal chunk writes the base tile.
__global__ __launch_bounds__(256) void flash_attn(const u16* __restrict__ Q,
                                                  const u16* __restrict__ K,
                                                  const u16* __restrict__ Vt,
                                                  float* __restrict__ ctx_base,
                                                  float* __restrict__ slots,
                                                  float* __restrict__ l_acc) {
    __shared__ __align__(16) u16 Kls[2][32 * 128];   // rows k (256B), swizzled
    __shared__ __align__(16) u16 Vls[2][128 * 32];   // rows e (64B)

    int lane = threadIdx.x & 63;
    int w    = threadIdx.x >> 6;          // 0..3
    int c = lane & 15, g = lane >> 4;

    int bid  = blockIdx.x;
    int head = bid & 7;                   // b*H + h
    int i    = bid >> 3;                  // 0..79
    int t, ch;
    if      (i < 8)  { t = 8 + i; ch = 0; }
    else if (i < 24) { int f = i - 8;  t = 16 + (f >> 1); ch = f & 1; }
    else if (i < 48) { int f = i - 24; t = 24 + f / 3;    ch = f % 3; }
    else             { int d = i - 48; t = ((d & 3) << 3) + (7 - (d >> 2)); ch = d & 3; }

    int kstart = ch << 10;
    int kend   = min(t * 128 + 128, kstart + 1024);
    int nsteps = (kend - kstart) >> 5;    // exact multiple

    int qb = t * 128 + w * 32;
    int my_steps = min(nsteps, ((qb + 31 - kstart) >> 5) + 1);

    // Q B-fragments for two q-halves (n=c=q-row, k=g*8..)
    short8 bq0[4], bq1[4];
    {
        const u16* qp0 = Q + ((size_t)head * LL + qb + c) * DD + g * 8;
        const u16* qp1 = qp0 + 16 * DD;
#pragma unroll
        for (int kk = 0; kk < 4; kk++) {
            bq0[kk] = *(const short8*)(qp0 + kk * 32);
            bq1[kk] = *(const short8*)(qp1 + kk * 32);
        }
    }

    floatx4 o0[8], o1[8];
#pragma unroll
    for (int tt = 0; tt < 8; tt++) {
        o0[tt] = (floatx4){0.f, 0.f, 0.f, 0.f};
        o1[tt] = (floatx4){0.f, 0.f, 0.f, 0.f};
    }
    float lsum0 = 0.f, lsum1 = 0.f;

    int s0 = c + (((g << 1) & 3) << 4);
    int s1 = c + ((((g << 1) | 1) & 3) << 4);
    bool hi = (g >= 2);

    const u16* Kg0 = K  + ((size_t)head * LL + kstart) * DD;
    const u16* Vg0 = Vt + (size_t)head * DD * LL + kstart;

    int q0 = w * 64 + lane;
    int r0 = q0 >> 4, cc0 = (q0 & 15) ^ (r0 & 15);
    int r1 = r0 + 16,  cc1 = (q0 & 15) ^ (r1 & 15);
    int e0 = q0 >> 2, c40 = (q0 & 3) * 8;
    int e1 = e0 + 64;

#define STAGE(s) {                                                          \
        int buf_ = (s) & 1; int kb_ = (s) << 5;                             \
        const u16* Kg = Kg0 + (size_t)kb_ * DD;                             \
        const u16* Vg = Vg0 + kb_;                                          \
        gld16(Kg + r0 * DD + cc0 * 8, &Kls[buf_][w * 512]);                 \
        gld16(Kg + r1 * DD + cc1 * 8, &Kls[buf_][2048 + w * 512]);          \
        gld16(Vg + (size_t)e0 * LL + c40, &Vls[buf_][w * 512]);             \
        gld16(Vg + (size_t)e1 * LL + c40, &Vls[buf_][2048 + w * 512]);      \
    }

    STAGE(0);

    for (int j = 0; j < nsteps; ++j) {
        __syncthreads();
        if (j + 1 < nsteps) STAGE(j + 1);
        if (j < my_steps) {
            int kb = kstart + (j << 5);
            const u16* Kb_ = &Kls[j & 1][0];
            const u16* Vb_ = &Vls[j & 1][0];

            floatx4 st00 = {0,0,0,0}, st01 = {0,0,0,0};
            floatx4 st10 = {0,0,0,0}, st11 = {0,0,0,0};
            {
                short8 ka[4];
#pragma unroll
                for (int kk = 0; kk < 4; kk++)
                    ka[kk] = *(const short8*)(Kb_ + c * 128 + (((g + 4 * kk) ^ c)) * 8);
#pragma unroll
                for (int kk = 0; kk < 4; kk++) {
                    st00 = __builtin_amdgcn_mfma_f32_16x16x32_bf16(ka[kk], bq0[kk], st00, 0, 0, 0);
                    st10 = __builtin_amdgcn_mfma_f32_16x16x32_bf16(ka[kk], bq1[kk], st10, 0, 0, 0);
                }
#pragma unroll
                for (int kk = 0; kk < 4; kk++)
                    ka[kk] = *(const short8*)(Kb_ + (16 + c) * 128 + (((g + 4 * kk) ^ c)) * 8);
#pragma unroll
                for (int kk = 0; kk < 4; kk++) {
                    st01 = __builtin_amdgcn_mfma_f32_16x16x32_bf16(ka[kk], bq0[kk], st01, 0, 0, 0);
                    st11 = __builtin_amdgcn_mfma_f32_16x16x32_bf16(ka[kk], bq1[kk], st11, 0, 0, 0);
                }
            }

            PFrag au0, au1;
#pragma unroll
            for (int qh = 0; qh < 2; qh++) {
                floatx4 sa = qh ? st10 : st00;
                floatx4 sb = qh ? st11 : st01;
                int qbh = qb + qh * 16;
                float p[8];
                if (kb + 31 > qbh) {
                    int q_c = qbh + c;
#pragma unroll
                    for (int r = 0; r < 4; r++) {
                        int k0 = kb + g * 4 + r;
                        p[r]     = (k0      <= q_c) ? sa[r] : -INFINITY;
                        p[4 + r] = (k0 + 16 <= q_c) ? sb[r] : -INFINITY;
                    }
                } else {
#pragma unroll
                    for (int r = 0; r < 4; r++) { p[r] = sa[r]; p[4 + r] = sb[r]; }
                }
                float ls = 0.f;
#pragma unroll
                for (int i2 = 0; i2 < 8; i2++) { p[i2] = __expf(p[i2]); ls += p[i2]; }
                if (qh) lsum1 += ls; else lsum0 += ls;

                u32 pk00 = (u32)f2bf(p[0]) | ((u32)f2bf(p[1]) << 16);
                u32 pk01 = (u32)f2bf(p[2]) | ((u32)f2bf(p[3]) << 16);
                u32 pk10 = (u32)f2bf(p[4]) | ((u32)f2bf(p[5]) << 16);
                u32 pk11 = (u32)f2bf(p[6]) | ((u32)f2bf(p[7]) << 16);
                u32 x00 = (u32)__shfl((int)pk00, s0), x10 = (u32)__shfl((int)pk10, s0);
                u32 x01 = (u32)__shfl((int)pk01, s0), x11 = (u32)__shfl((int)pk11, s0);
                u32 y00 = (u32)__shfl((int)pk00, s1), y10 = (u32)__shfl((int)pk10, s1);
                u32 y01 = (u32)__shfl((int)pk01, s1), y11 = (u32)__shfl((int)pk11, s1);
                PFrag* au = qh ? &au1 : &au0;
                au->u[0] = hi ? x10 : x00;
                au->u[1] = hi ? x11 : x01;
                au->u[2] = hi ? y10 : y00;
                au->u[3] = hi ? y11 : y01;
            }

#pragma unroll
            for (int tt = 0; tt < 8; tt++) {
                short8 vb = *(const short8*)(Vb_ + (tt * 16 + c) * 32 + g * 8);
                o0[tt] = __builtin_amdgcn_mfma_f32_16x16x32_bf16(au0.s, vb, o0[tt], 0, 0, 0);
                o1[tt] = __builtin_amdgcn_mfma_f32_16x16x32_bf16(au1.s, vb, o1[tt], 0, 0, 0);
            }
        }
    }
#undef STAGE

    lsum0 += __shfl_xor(lsum0, 16); lsum0 += __shfl_xor(lsum0, 32);
    lsum1 += __shfl_xor(lsum1, 16); lsum1 += __shfl_xor(lsum1, 32);
    if (g == 0) {
        atomicAdd(&l_acc[head * LL + qb + c],      lsum0);
        atomicAdd(&l_acc[head * LL + qb + 16 + c], lsum1);
    }

    bool diag = (ch == (t >> 3));
    float* dst0 = diag ? ctx_base + ((size_t)head * LL + t * 128) * 128
                       : slots + (size_t)(head * 48 + pfx(t) + ch) * 16384;
    dst0 += (size_t)(w * 32) * 128;
#pragma unroll
    for (int r = 0; r < 4; r++) {
        float* d0 = dst0 + (g * 4 + r) * 128 + c;
        float* d1 = d0 + 16 * 128;
#pragma unroll
        for (int tt = 0; tt < 8; tt++) {
            d0[tt * 16] = o0[tt][r];
            d1[tt * 16] = o1[tt][r];
        }
    }
}

// ctx_bf16 = f2bf((base + sum slots) / l)
__global__ __launch_bounds__(256) void norm_cast(const float* __restrict__ base,
                                                 const float* __restrict__ slots,
                                                 const float* __restrict__ l_acc,
                                                 u16* __restrict__ ctx) {
    int i = blockIdx.x * 256 + threadIdx.x;
    int e4 = i * 4;
    int col = e4 & 511;
    int bl  = e4 >> 9;
    int b_ = bl >> 12, l = bl & 4095;
    int h = col >> 7, d = col & 127;
    int head = b_ * HH + h;
    int t = l >> 7;
    int nx = t >> 3;

    float4 v = *(const float4*)(base + ((size_t)head * LL + l) * 128 + d);
    if (nx > 0) {
        int sb = head * 48 + pfx(t);
        for (int x = 0; x < nx; x++) {
            float4 sv = *(const float4*)(slots + (size_t)(sb + x) * 16384 + (l & 127) * 128 + d);
            v.x += sv.x; v.y += sv.y; v.z += sv.z; v.w += sv.w;
        }
    }
    float inv = 1.f / l_acc[head * LL + l];
    ushort4 o;
    o.x = f2bf(v.x * inv); o.y = f2bf(v.y * inv);
    o.z = f2bf(v.z * inv); o.w = f2bf(v.w * inv);
    *(ushort4*)(ctx + e4) = o;
}

// y = ctx(8192x512) @ Wo(128x512)^T -> fp32 [B,L,128]
// 64 blocks of 128x128, K=512 in 8 double-buffered 64-chunks.
__global__ __launch_bounds__(256) void proj_out(const u16* __restrict__ ctx,
                                                const u16* __restrict__ wo,
                                                float* __restrict__ y) {
    __shared__ __align__(16) u16 At[2][128 * 64];
    __shared__ __align__(16) u16 Wt[2][128 * 64];
    int lane = threadIdx.x & 63;
    int w    = threadIdx.x >> 6;
    int c = lane & 15, g = lane >> 4;
    int mt = blockIdx.x;                  // 0..63
    const u16* Ag = ctx + (size_t)mt * 128 * 512;

#define PSTAGE(kc) {                                                        \
        int buf_ = (kc) & 1; int ks_ = (kc) * 64;                           \
        _Pragma("unroll")                                                   \
        for (int i = 0; i < 4; i++) {                                       \
            int row = i * 32 + w * 8 + (lane >> 3);                         \
            int cc  = (lane & 7) ^ (row & 7);                               \
            gld16(Ag + (size_t)row * 512 + ks_ + cc * 8,                    \
                  &At[buf_][(i * 32 + w * 8) * 64]);                        \
            gld16(wo + (size_t)row * 512 + ks_ + cc * 8,                    \
                  &Wt[buf_][(i * 32 + w * 8) * 64]);                        \
        }                                                                   \
    }

    floatx4 acc[2][8];
#pragma unroll
    for (int m2 = 0; m2 < 2; m2++)
#pragma unroll
        for (int n2 = 0; n2 < 8; n2++) acc[m2][n2] = (floatx4){0.f, 0.f, 0.f, 0.f};

    PSTAGE(0);
    for (int kc = 0; kc < 8; kc++) {
        __syncthreads();
        if (kc + 1 < 8) PSTAGE(kc + 1);
        int buf = kc & 1;
#pragma unroll
        for (int kk = 0; kk < 2; kk++) {
            int G = g + 4 * kk;
            short8 a0, a1, bf[8];
            {
                int ra = w * 32 + c;
                int rb = ra + 16;
                a0 = *(const short8*)(&At[buf][ra * 64 + ((G ^ (ra & 7)) * 8)]);
                a1 = *(const short8*)(&At[buf][rb * 64 + ((G ^ (rb & 7)) * 8)]);
            }
#pragma unroll
            for (int n2 = 0; n2 < 8; n2++) {
                int rn = n2 * 16 + c;
                bf[n2] = *(const short8*)(&Wt[buf][rn * 64 + ((G ^ (rn & 7)) * 8)]);
            }
#pragma unroll
            for (int n2 = 0; n2 < 8; n2++) {
                acc[0][n2] = __builtin_amdgcn_mfma_f32_16x16x32_bf16(a0, bf[n2], acc[0][n2], 0, 0, 0);
                acc[1][n2] = __builtin_amdgcn_mfma_f32_16x16x32_bf16(a1, bf[n2], acc[1][n2], 0, 0, 0);
            }
        }
    }
#undef PSTAGE

#pragma unroll
    for (int m2 = 0; m2 < 2; m2++)
#pragma unroll
        for (int r = 0; r < 4; r++) {
            int m = mt * 128 + w * 32 + m2 * 16 + g * 4 + r;
            float* yp = y + (size_t)m * 128 + c;
#pragma unroll
            for (int n2 = 0; n2 < 8; n2++) yp[n2 * 16] = acc[m2][n2][r];
        }
}

extern "C" void kernel_launch(void* const* d_in, const int* in_sizes, int n_in,
                              void* d_out, int out_size, void* d_ws, size_t ws_size,
                              hipStream_t stream) {
    const float* x  = (const float*)d_in[0];
    const float* Wq = (const float*)d_in[1];
    const float* Wk = (const float*)d_in[2];
    const float* Wv = (const float*)d_in[3];
    const float* Wo = (const float*)d_in[4];
    float* y = (float*)d_out;

    u16* ws  = (u16*)d_ws;
    u16* xb  = ws;                          // 1,048,576
    u16* wqb = xb  + BB * LL * DD;          // 65,536 each
    u16* wkb = wqb + HH * DD * DD;
    u16* wvb = wkb + HH * DD * DD;
    u16* wob = wvb + HH * DD * DD;
    u16* Qb  = wob + DD * HH * DD;          // [B,H,L,128]
    u16* Kb  = Qb  + BB * HH * LL * DD;
    u16* Vt  = Kb  + BB * HH * LL * DD;     // [B,H,128,L]
    u16* ctx = Vt  + BB * HH * LL * DD;     // [B,L,512] bf16
    float* ctx_base = (float*)(ctx + (size_t)BB * LL * HH * DD);   // [8][L][128]
    float* slots    = ctx_base + (size_t)8 * LL * 128;             // 384 x 16384
    float* l_acc    = slots + (size_t)384 * 16384;                 // [8][L]

    cvt_all<<<dim3(1024, 6), 256, 0, stream>>>(x, Wq, Wk, Wv, Wo,
                                               xb, wqb, wkb, wvb, wob, l_acc);
    proj_qkv<<<dim3(64, 12), 256, 0, stream>>>(xb, wqb, wkb, wvb, Qb, Kb, Vt);
    flash_attn<<<dim3(640), 256, 0, stream>>>(Qb, Kb, Vt, ctx_base, slots, l_acc);
    norm_cast<<<dim3(4096), 256, 0, stream>>>(ctx_base, slots, l_acc, ctx);
    proj_out<<<dim3(64), 256, 0, stream>>>(ctx, wob, y);
}